// Round 19
// baseline (302.405 us; speedup 1.0000x reference)
//
#include <hip/hip_runtime.h>
#include <stdint.h>

// LRU forward: y = Re(scan(lam, gamma*(x@B^T)) @ C^T) + x @ D^T
// Round 19: r18 engine + (1) out_mfma's three GEMMs fused into ONE 64-virtual-tile
// pipeline (removes 2 vmcnt(0) drains + 2 prologue stalls per block); (2) params_k
// folded into wround_all (one launch fewer). Everything else identical to r18.

#define BSZ   8
#define TLEN  4096
#define DIN   1024
#define DOUT  1024
#define NST   512
#define M_TOT (BSZ * TLEN)   // 32768
#define NC    32
#define CL    128

// 256-tile engine
#define WOFF  8192           // W region offset (A region = 256x32 shorts = 16KB)
#define NBUF  16384          // shorts per buffer (32KB): A@0, W@8192

// fallback engine (r14, 128x256)
#define PLA   4096
#define OBUFS 12288

typedef __attribute__((ext_vector_type(8))) short bf16x8;
typedef __attribute__((ext_vector_type(4))) float f32x4;

// ---- bf16 helpers -------------------------------------------------------------------------
__device__ __forceinline__ float s2f(short s) {
  unsigned v = ((unsigned)(unsigned short)s) << 16;
  return __builtin_bit_cast(float, v);
}
__device__ __forceinline__ short f2s_rne(float f) {
  unsigned u = __builtin_bit_cast(unsigned, f);
  unsigned r = (u + 0x7FFFu + ((u >> 16) & 1u)) >> 16;
  return (short)r;
}
__device__ __forceinline__ void round8(const float4 v0, const float4 v1, bf16x8& hv) {
  const float f[8] = {v0.x, v0.y, v0.z, v0.w, v1.x, v1.y, v1.z, v1.w};
  #pragma unroll
  for (int j = 0; j < 8; ++j) hv[j] = f2s_rne(f[j]);
}

// ---- async global->LDS, 16B per lane ------------------------------------------------------
__device__ __forceinline__ void gload16(const short* g, short* l) {
  __builtin_amdgcn_global_load_lds(
      (const __attribute__((address_space(1))) void*)g,
      (__attribute__((address_space(3))) void*)l, 16, 0, 0);
}

// Quad-XOR swizzle (r5-r18, measured 0 conflicts): data quad q of row r lives at slot
// quad q^((r>>1)&3); DMA dest linear, SOURCE pre-permuted, ds_read applies the XOR.

// ---- one staging load (chunk ch of a 256-tile: 0-15 A rows, 16-31 W rows) -----------------
__device__ __forceinline__ void stage_one256(
    const short* __restrict__ Ag, const short* __restrict__ Wg,
    const int ld, const int m0, const int n0, const int k0,
    short* lbuf, const int ch, const int lane)
{
  const int q  = (lane & 3) ^ ((lane >> 3) & 3);
  const int gr = lane >> 2;
  const short* g;
  int r0, dst;
  if (ch < 16) { g = Ag; r0 = m0 + ch * 16;        dst = ch * 512; }
  else         { g = Wg; r0 = n0 + (ch - 16) * 16; dst = WOFF + (ch - 16) * 512; }
  gload16(g + (size_t)(r0 + gr) * ld + k0 + q * 8, lbuf + dst);
}

// ---- 256-tile pipelined GEMM (single segment, used by bu_mfma) ----------------------------
template<int NT>
__device__ __forceinline__ void gemm256(
    const short* __restrict__ Ap, const short* __restrict__ Wp,
    const int ld, const int m0, const int n0, const int tid,
    f32x4 (&acc)[8][4], short* lds)
{
  const int lane = tid & 63, w = tid >> 6, wm = w >> 2, wn = w & 3;
  const int lr = lane & 15, kg = lane >> 4;
  const int qo = (kg ^ ((lr >> 1) & 3)) * 8;

  #pragma unroll
  for (int j = 0; j < 4; ++j)
    stage_one256(Ap, Wp, ld, m0, n0, 0, lds, w * 4 + j, lane);
  #pragma unroll
  for (int j = 0; j < 4; ++j)
    stage_one256(Ap, Wp, ld, m0, n0, 32, lds + NBUF, w * 4 + j, lane);

  int c0 = 0;
  for (int k = 0; k < NT; ++k) {
    short* cur = lds + c0 * NBUF;
    int cs = c0 + 2; if (cs >= 3) cs -= 3;
    short* nx2 = lds + cs * NBUF;

    if (k + 1 < NT) asm volatile("s_waitcnt vmcnt(4)" ::: "memory");
    else            asm volatile("s_waitcnt vmcnt(0)" ::: "memory");
    __builtin_amdgcn_s_barrier();

    bf16x8 wv[4];
    #pragma unroll
    for (int ph = 0; ph < 4; ++ph) {
      if (ph == 0) {
        #pragma unroll
        for (int nf = 0; nf < 4; ++nf)
          wv[nf] = *(const bf16x8*)&cur[WOFF + (wn * 64 + nf * 16 + lr) * 32 + qo];
      }
      const int mi0 = ph * 2;
      const bf16x8 a0 = *(const bf16x8*)&cur[(wm * 128 + mi0 * 16 + lr) * 32 + qo];
      const bf16x8 a1 = *(const bf16x8*)&cur[(wm * 128 + (mi0 + 1) * 16 + lr) * 32 + qo];
      if (k + 2 < NT)
        stage_one256(Ap, Wp, ld, m0, n0, (k + 2) * 32, nx2, w * 4 + ph, lane);
      __builtin_amdgcn_s_barrier();
      asm volatile("s_waitcnt lgkmcnt(0)" ::: "memory");
      __builtin_amdgcn_sched_barrier(0);
      __builtin_amdgcn_s_setprio(1);
      #pragma unroll
      for (int nf = 0; nf < 4; ++nf) {
        acc[mi0][nf]     = __builtin_amdgcn_mfma_f32_16x16x32_bf16(a0, wv[nf], acc[mi0][nf], 0, 0, 0);
        acc[mi0 + 1][nf] = __builtin_amdgcn_mfma_f32_16x16x32_bf16(a1, wv[nf], acc[mi0 + 1][nf], 0, 0, 0);
      }
      __builtin_amdgcn_s_setprio(0);
      __builtin_amdgcn_s_barrier();
    }
    c0 = (c0 == 2) ? 0 : c0 + 1;
  }
}

// ---- virtual-tile map for the fused out pipeline: 64 tiles over 3 segments ----------------
// v in [0,16): st_re x Crw (K=512); [16,32): st_im x Ciw; [32,64): xw x Dw (K=1024).
__device__ __forceinline__ void map_virt(const int v,
    const short* st_re, const short* st_im, const short* xw,
    const short* Crw, const short* Ciw, const short* Dw,
    const short*& A, const short*& W, int& ld, int& k0)
{
  if (v < 16)      { A = st_re; W = Crw; ld = NST; k0 = v * 32; }
  else if (v < 32) { A = st_im; W = Ciw; ld = NST; k0 = (v - 16) * 32; }
  else             { A = xw;    W = Dw;  ld = DIN; k0 = (v - 32) * 32; }
}

// ---- fused 64-virtual-tile pipeline (out_mfma) --------------------------------------------
__device__ __forceinline__ void gemm_out_fused(
    const short* __restrict__ st_re, const short* __restrict__ st_im,
    const short* __restrict__ xw,
    const short* __restrict__ Crw, const short* __restrict__ Ciw,
    const short* __restrict__ Dw,
    const int m0, const int o0, const int tid,
    f32x4 (&acc)[8][4], short* lds)
{
  const int lane = tid & 63, w = tid >> 6, wm = w >> 2, wn = w & 3;
  const int lr = lane & 15, kg = lane >> 4;
  const int qo = (kg ^ ((lr >> 1) & 3)) * 8;
  const short *A, *W;
  int ld, k0;

  map_virt(0, st_re, st_im, xw, Crw, Ciw, Dw, A, W, ld, k0);
  #pragma unroll
  for (int j = 0; j < 4; ++j)
    stage_one256(A, W, ld, m0, o0, k0, lds, w * 4 + j, lane);
  map_virt(1, st_re, st_im, xw, Crw, Ciw, Dw, A, W, ld, k0);
  #pragma unroll
  for (int j = 0; j < 4; ++j)
    stage_one256(A, W, ld, m0, o0, k0, lds + NBUF, w * 4 + j, lane);

  int c0 = 0;
  for (int v = 0; v < 64; ++v) {
    short* cur = lds + c0 * NBUF;
    int cs = c0 + 2; if (cs >= 3) cs -= 3;
    short* nx2 = lds + cs * NBUF;

    if (v + 1 < 64) asm volatile("s_waitcnt vmcnt(4)" ::: "memory");  // tile-v landed,
    else            asm volatile("s_waitcnt vmcnt(0)" ::: "memory");  // v+1 stays in flight
    __builtin_amdgcn_s_barrier();

    const bool pre = (v + 2 < 64);
    if (pre) map_virt(v + 2, st_re, st_im, xw, Crw, Ciw, Dw, A, W, ld, k0);

    bf16x8 wv[4];
    #pragma unroll
    for (int ph = 0; ph < 4; ++ph) {
      if (ph == 0) {
        #pragma unroll
        for (int nf = 0; nf < 4; ++nf)
          wv[nf] = *(const bf16x8*)&cur[WOFF + (wn * 64 + nf * 16 + lr) * 32 + qo];
      }
      const int mi0 = ph * 2;
      const bf16x8 a0 = *(const bf16x8*)&cur[(wm * 128 + mi0 * 16 + lr) * 32 + qo];
      const bf16x8 a1 = *(const bf16x8*)&cur[(wm * 128 + (mi0 + 1) * 16 + lr) * 32 + qo];
      if (pre)                               // spread staging: 1 load/phase, tile v+2
        stage_one256(A, W, ld, m0, o0, k0, nx2, w * 4 + ph, lane);
      __builtin_amdgcn_s_barrier();
      asm volatile("s_waitcnt lgkmcnt(0)" ::: "memory");
      __builtin_amdgcn_sched_barrier(0);
      __builtin_amdgcn_s_setprio(1);
      #pragma unroll
      for (int nf = 0; nf < 4; ++nf) {
        acc[mi0][nf]     = __builtin_amdgcn_mfma_f32_16x16x32_bf16(a0, wv[nf], acc[mi0][nf], 0, 0, 0);
        acc[mi0 + 1][nf] = __builtin_amdgcn_mfma_f32_16x16x32_bf16(a1, wv[nf], acc[mi0 + 1][nf], 0, 0, 0);
      }
      __builtin_amdgcn_s_setprio(0);
      __builtin_amdgcn_s_barrier();
    }
    c0 = (c0 == 2) ? 0 : c0 + 1;
  }
}

// ---- XCD map for 512-block grid: 128 m-blocks x 4 n-blocks --------------------------------
__device__ __forceinline__ void map256(const int bid, int& mb, int& nb) {
  const int xcd = bid & 7;
  const int j   = bid >> 3;       // 0..63
  mb = xcd * 16 + (j >> 2);       // 0..127
  nb = j & 3;                     // 0..3
}

// ==================== fallback engine (r14, 128x256 tile) — !full path only ================
__device__ __forceinline__ void stage_cx(
    const short* __restrict__ Ag, const short* __restrict__ Wg,
    const int lda, const int ldb, const int m0, const int n0, const int k0,
    short* lbuf, const int w, const int lane)
{
  const int q  = (lane & 3) ^ ((lane >> 3) & 3);
  const int gr = lane >> 2;
  #pragma unroll
  for (int j = 0; j < 3; ++j) {
    const int ch = w * 3 + j;
    const short* g;
    int r0, ld, dst;
    if (ch < 8) { g = Ag; r0 = m0 + ch * 16;        ld = lda; dst = ch * 512; }
    else        { g = Wg; r0 = n0 + (ch - 8) * 16;  ld = ldb; dst = PLA + (ch - 8) * 512; }
    gload16(g + (size_t)(r0 + gr) * ld + k0 + q * 8, lbuf + dst);
  }
}

__device__ __forceinline__ void gemm_fb(
    const float* __restrict__ Af, const short* __restrict__ Wp,
    const int lda, const int ldb, const int K, const int m0, const int n0, const int tid,
    f32x4 (&acc)[4][4], short* lds)          // single buffer: A@0, W@PLA
{
  const int lane = tid & 63, w = tid >> 6, wm = w >> 2, wn = w & 3;
  const int r = tid & 127, e = (tid >> 7) & 3;
  float4 pa[2];
  {
    const float* p = Af + (size_t)(m0 + r) * lda + e * 8;
    pa[0] = *(const float4*)(p);
    pa[1] = *(const float4*)(p + 4);
  }
  for (int k0 = 0; k0 < K; k0 += 32) {
    __syncthreads();
    {
      bf16x8 hv;
      round8(pa[0], pa[1], hv);
      const int f = (r >> 1) & 3;
      *(bf16x8*)&lds[r * 32 + ((e ^ f) * 8)] = hv;
    }
    {
      const int q = (lane & 3) ^ ((lane >> 3) & 3);
      const int gr = lane >> 2;
      #pragma unroll
      for (int i = 0; i < 2; ++i)
        gload16(Wp + (size_t)(n0 + (2 * w + i) * 16 + gr) * ldb + k0 + q * 8,
                lds + PLA + (2 * w + i) * 512);
    }
    __syncthreads();
    if (k0 + 32 < K) {
      const float* p = Af + (size_t)(m0 + r) * lda + (k0 + 32) + e * 8;
      pa[0] = *(const float4*)(p);
      pa[1] = *(const float4*)(p + 4);
    }
    const int lr = lane & 15, kg = lane >> 4;
    const int qo = (kg ^ ((lr >> 1) & 3)) * 8;
    bf16x8 aw[4], bw[4];
    #pragma unroll
    for (int mi = 0; mi < 4; ++mi)
      aw[mi] = *(const bf16x8*)&lds[(wm * 64 + mi * 16 + lr) * 32 + qo];
    #pragma unroll
    for (int ni = 0; ni < 4; ++ni)
      bw[ni] = *(const bf16x8*)&lds[PLA + (wn * 64 + ni * 16 + lr) * 32 + qo];
    #pragma unroll
    for (int ni = 0; ni < 4; ++ni)
      #pragma unroll
      for (int mi = 0; mi < 4; ++mi)
        acc[mi][ni] = __builtin_amdgcn_mfma_f32_16x16x32_bf16(aw[mi], bw[ni], acc[mi][ni], 0, 0, 0);
  }
  __syncthreads();
}

template<int NT>
__device__ __forceinline__ void gemm_pl(
    const short* __restrict__ Ap, const short* __restrict__ Wp,
    const int lda, const int ldb, const int m0, const int n0, const int tid,
    f32x4 (&acc)[4][4], short* lds)
{
  const int lane = tid & 63, w = tid >> 6, wm = w >> 2, wn = w & 3;
  const int lr = lane & 15, kg = lane >> 4;
  const int qo = (kg ^ ((lr >> 1) & 3)) * 8;
  stage_cx(Ap, Wp, lda, ldb, m0, n0, 0, lds, w, lane);
  for (int k = 0; k < NT; ++k) {
    short* cur = lds + (k & 1) * OBUFS;
    if (k + 1 < NT) {
      stage_cx(Ap, Wp, lda, ldb, m0, n0, (k + 1) * 32, lds + ((k + 1) & 1) * OBUFS, w, lane);
      asm volatile("s_waitcnt vmcnt(3)" ::: "memory");
    } else {
      asm volatile("s_waitcnt vmcnt(0)" ::: "memory");
    }
    __builtin_amdgcn_s_barrier();
    bf16x8 bw[4];
    #pragma unroll
    for (int ph = 0; ph < 2; ++ph) {
      if (ph == 0) {
        #pragma unroll
        for (int ni = 0; ni < 4; ++ni)
          bw[ni] = *(const bf16x8*)&cur[PLA + (wn * 64 + ni * 16 + lr) * 32 + qo];
      }
      const int mi0 = ph * 2;
      const bf16x8 a0 = *(const bf16x8*)&cur[(wm * 64 + mi0 * 16 + lr) * 32 + qo];
      const bf16x8 a1 = *(const bf16x8*)&cur[(wm * 64 + (mi0 + 1) * 16 + lr) * 32 + qo];
      __builtin_amdgcn_s_barrier();
      asm volatile("s_waitcnt lgkmcnt(0)" ::: "memory");
      __builtin_amdgcn_sched_barrier(0);
      __builtin_amdgcn_s_setprio(1);
      #pragma unroll
      for (int ni = 0; ni < 4; ++ni) {
        acc[mi0][ni]     = __builtin_amdgcn_mfma_f32_16x16x32_bf16(a0, bw[ni], acc[mi0][ni], 0, 0, 0);
        acc[mi0 + 1][ni] = __builtin_amdgcn_mfma_f32_16x16x32_bf16(a1, bw[ni], acc[mi0 + 1][ni], 0, 0, 0);
      }
      __builtin_amdgcn_s_setprio(0);
      __builtin_amdgcn_s_barrier();
    }
  }
}

__device__ __forceinline__ void map_mn4(const int bid, int& mb, int& nb) {
  const int xcd = bid & 7;
  const int j   = bid >> 3;
  mb = xcd * 32 + (j >> 2);
  nb = j & 3;
}
// ===========================================================================================

// ---- fused preprocessing: all weight/x planes + scan params in one launch -----------------
__global__ __launch_bounds__(256) void wround_all(
    const float* __restrict__ Bre, const float* __restrict__ Bim,
    const float* __restrict__ Cre, const float* __restrict__ Cim,
    const float* __restrict__ Dm,  const float* __restrict__ x,
    short* __restrict__ Brw, short* __restrict__ Biw,
    short* __restrict__ Crw, short* __restrict__ Ciw,
    short* __restrict__ Dw,  short* __restrict__ xw,
    const float* __restrict__ nulog, const float* __restrict__ thlog,
    const float* __restrict__ glog,
    float2* __restrict__ lam, float2* __restrict__ lamL, float* __restrict__ gamma,
    const int nB4, const int nC4, const int nD4, const int nX4)
{
  int o = blockIdx.x * 256 + threadIdx.x;
  const float* src; short* dst; float sgn = 1.0f;
  if (o < nB4)              { src = Bre; dst = Brw; }
  else if ((o -= nB4) < nB4){ src = Bim; dst = Biw; }
  else if ((o -= nB4) < nC4){ src = Cre; dst = Crw; }
  else if ((o -= nC4) < nC4){ src = Cim; dst = Ciw; sgn = -1.0f; }
  else if ((o -= nC4) < nD4){ src = Dm;  dst = Dw; }
  else if ((o -= nD4) < nX4){ src = x;   dst = xw; }
  else if ((o -= nX4) < NST){               // scan params tail
    const int n = o;
    const float nu = expf(nulog[n]);
    const float th = expf(thlog[n]);
    const float mod = expf(-nu);
    float s, c;
    sincosf(th, &s, &c);
    lam[n] = make_float2(mod * c, mod * s);
    const float modL = expf(-(float)CL * nu);
    float sL, cL;
    sincosf((float)CL * th, &sL, &cL);
    lamL[n] = make_float2(modL * cL, modL * sL);
    gamma[n] = expf(glog[n]);
    return;
  }
  else return;
  const float4 v = ((const float4*)src)[o];
  short4 hv;
  hv.x = f2s_rne(sgn * v.x); hv.y = f2s_rne(sgn * v.y);
  hv.z = f2s_rne(sgn * v.z); hv.w = f2s_rne(sgn * v.w);
  ((short4*)dst)[o] = hv;
}

// ---- kernel 1 (256 engine): Bu = rne(gamma * (x @ [Bre|Bim]^T)) ---------------------------
__global__ __launch_bounds__(512, 2) void bu_mfma(
    const short* __restrict__ xw,
    const short* __restrict__ Brw, const short* __restrict__ Biw,
    const float* __restrict__ gamma,
    short* __restrict__ bu_re, short* __restrict__ bu_im)
{
  __shared__ short lds[3 * NBUF];          // 96 KB
  f32x4 acc[8][4] = {};
  const int tid = threadIdx.x;
  int mb, nbk;
  map256(blockIdx.x, mb, nbk);
  const int m0  = mb * 256;
  const int n0s = nbk * 256;               // 0,256 -> re; 512,768 -> im
  const bool re = (n0s < NST);
  const int nb0 = n0s & (NST - 1);

  gemm256<32>(xw, re ? Brw : Biw, DIN, m0, nb0, tid, acc, lds);

  short* Hp = re ? bu_re : bu_im;
  const int lane = tid & 63, w = tid >> 6, wm = w >> 2, wn = w & 3;
  const int lr = lane & 15, lq = lane >> 4;
  #pragma unroll
  for (int nf = 0; nf < 4; ++nf) {
    const int nb = nb0 + wn * 64 + nf * 16 + lr;
    const float g = gamma[nb];
    #pragma unroll
    for (int mf = 0; mf < 8; ++mf)
      #pragma unroll
      for (int j = 0; j < 4; ++j) {
        const size_t m = (size_t)m0 + wm * 128 + mf * 16 + lq * 4 + j;
        Hp[m * NST + nb] = f2s_rne(acc[mf][nf][j] * g);
      }
  }
}

// ---- fallback bu (r14 engine) -------------------------------------------------------------
__global__ __launch_bounds__(512, 4) void bu_fb(
    const float* __restrict__ x,
    const short* __restrict__ Brw, const short* __restrict__ Biw,
    const float* __restrict__ gamma,
    short* __restrict__ bu_re, short* __restrict__ bu_im)
{
  __shared__ short lds[2 * OBUFS];
  f32x4 acc[4][4] = {};
  const int tid = threadIdx.x;
  int mb, nbk;
  map_mn4(blockIdx.x, mb, nbk);
  const int m0  = mb * 128;
  const int n0s = nbk * 256;
  const bool re = (n0s < NST);
  const int nb0 = n0s & (NST - 1);
  gemm_fb(x, re ? Brw : Biw, DIN, DIN, DIN, m0, nb0, tid, acc, lds);
  short* Hp = re ? bu_re : bu_im;
  const int lane = tid & 63, w = tid >> 6, wm = w >> 2, wn = w & 3;
  const int lr = lane & 15, lq = lane >> 4;
  #pragma unroll
  for (int ni = 0; ni < 4; ++ni) {
    const int nb = nb0 + wn * 64 + ni * 16 + lr;
    const float g = gamma[nb];
    #pragma unroll
    for (int mi = 0; mi < 4; ++mi)
      #pragma unroll
      for (int j = 0; j < 4; ++j) {
        const size_t m = (size_t)m0 + wm * 64 + mi * 16 + lq * 4 + j;
        Hp[m * NST + nb] = f2s_rne(acc[mi][ni][j] * g);
      }
  }
}

// ---- scan phase 1: 2-n per thread (short2), single-plane Bu -------------------------------
__global__ __launch_bounds__(256) void scan_partial(
    const short* __restrict__ bu_re, const short* __restrict__ bu_im,
    const float2* __restrict__ lam, float2* __restrict__ carry)
{
  const int g = blockIdx.x * 256 + threadIdx.x;
  const int n2 = g & 255;
  const int c  = (g >> 8) & (NC - 1);
  const int b  = g >> 13;
  const int n  = n2 * 2;
  const float2 L0 = lam[n], L1 = lam[n + 1];
  const short2* R = (const short2*)bu_re;
  const short2* I = (const short2*)bu_im;
  size_t idx = ((size_t)b * TLEN + (size_t)c * CL) * (NST / 2) + n2;
  float sr0 = 0.f, si0 = 0.f, sr1 = 0.f, si1 = 0.f;
  #pragma unroll 4
  for (int t = 0; t < CL; ++t, idx += NST / 2) {
    const short2 vr = R[idx], vi = I[idx];
    const float br0 = s2f(vr.x), br1 = s2f(vr.y);
    const float bi0 = s2f(vi.x), bi1 = s2f(vi.y);
    float nr = fmaf(L0.x, sr0, fmaf(-L0.y, si0, br0));
    float ni = fmaf(L0.x, si0, fmaf( L0.y, sr0, bi0));
    sr0 = nr; si0 = ni;
    nr = fmaf(L1.x, sr1, fmaf(-L1.y, si1, br1));
    ni = fmaf(L1.x, si1, fmaf( L1.y, sr1, bi1));
    sr1 = nr; si1 = ni;
  }
  const size_t cb = (size_t)(b * NC + c) * NST + n;
  carry[cb]     = make_float2(sr0, si0);
  carry[cb + 1] = make_float2(sr1, si1);
}

// ---- scan phase 2 -------------------------------------------------------------------------
__global__ __launch_bounds__(256) void scan_carry(
    float2* __restrict__ carry, const float2* __restrict__ lamL)
{
  const int g = blockIdx.x * 256 + threadIdx.x;
  const int n = g & (NST - 1);
  const int b = g >> 9;
  const float2 P = lamL[n];
  float sr = 0.f, si = 0.f;
  for (int c = 0; c < NC; ++c) {
    const size_t idx = (size_t)(b * NC + c) * NST + n;
    const float2 v = carry[idx];
    carry[idx] = make_float2(sr, si);
    const float nr = fmaf(P.x, sr, fmaf(-P.y, si, v.x));
    const float ni = fmaf(P.x, si, fmaf( P.y, sr, v.y));
    sr = nr; si = ni;
  }
}

// ---- scan phase 3: re-scan with carry-in, states overwrite Bu (single bf16) ---------------
__global__ __launch_bounds__(256) void scan_final(
    short* __restrict__ bu_re, short* __restrict__ bu_im,
    const float2* __restrict__ lam, const float2* __restrict__ carry)
{
  const int g = blockIdx.x * 256 + threadIdx.x;
  const int n2 = g & 255;
  const int c  = (g >> 8) & (NC - 1);
  const int b  = g >> 13;
  const int n  = n2 * 2;
  const float2 L0 = lam[n], L1 = lam[n + 1];
  const size_t cb = (size_t)(b * NC + c) * NST + n;
  const float2 ci0 = carry[cb], ci1 = carry[cb + 1];
  short2* R = (short2*)bu_re;
  short2* I = (short2*)bu_im;
  size_t idx = ((size_t)b * TLEN + (size_t)c * CL) * (NST / 2) + n2;
  float sr0 = ci0.x, si0 = ci0.y, sr1 = ci1.x, si1 = ci1.y;
  #pragma unroll 4
  for (int t = 0; t < CL; ++t, idx += NST / 2) {
    const short2 vr = R[idx], vi = I[idx];
    const float br0 = s2f(vr.x), br1 = s2f(vr.y);
    const float bi0 = s2f(vi.x), bi1 = s2f(vi.y);
    float nr = fmaf(L0.x, sr0, fmaf(-L0.y, si0, br0));
    float ni = fmaf(L0.x, si0, fmaf( L0.y, sr0, bi0));
    sr0 = nr; si0 = ni;
    nr = fmaf(L1.x, sr1, fmaf(-L1.y, si1, br1));
    ni = fmaf(L1.x, si1, fmaf( L1.y, sr1, bi1));
    sr1 = nr; si1 = ni;
    short2 so;
    so.x = f2s_rne(sr0); so.y = f2s_rne(sr1);
    R[idx] = so;
    so.x = f2s_rne(si0); so.y = f2s_rne(si1);
    I[idx] = so;
  }
}

// ---- kernel 5 (fused pipeline): y = st_re@Cre^T - st_im@Cim^T + x@D^T ---------------------
__global__ __launch_bounds__(512, 2) void out_mfma(
    const short* __restrict__ st_re, const short* __restrict__ st_im,
    const short* __restrict__ xw,
    const short* __restrict__ Crw, const short* __restrict__ Ciw,  // Cim pre-negated
    const short* __restrict__ Dw,
    float* __restrict__ y)
{
  __shared__ short lds[3 * NBUF];          // 96 KB
  f32x4 acc[8][4] = {};
  const int tid = threadIdx.x;
  int mb, nbk;
  map256(blockIdx.x, mb, nbk);
  const int m0 = mb * 256;
  const int o0 = nbk * 256;

  gemm_out_fused(st_re, st_im, xw, Crw, Ciw, Dw, m0, o0, tid, acc, lds);

  const int lane = tid & 63, w = tid >> 6, wm = w >> 2, wn = w & 3;
  const int lr = lane & 15, lq = lane >> 4;
  #pragma unroll
  for (int mf = 0; mf < 8; ++mf)
    #pragma unroll
    for (int j = 0; j < 4; ++j) {
      const size_t m = (size_t)m0 + wm * 128 + mf * 16 + lq * 4 + j;
      #pragma unroll
      for (int nf = 0; nf < 4; ++nf)
        y[m * DOUT + o0 + wn * 64 + nf * 16 + lr] = acc[mf][nf][j];
    }
}

// ---- fallback out (r14 engine) ------------------------------------------------------------
__global__ __launch_bounds__(512, 4) void out_fb(
    const short* __restrict__ st_re, const short* __restrict__ st_im,
    const float* __restrict__ x,
    const short* __restrict__ Crw, const short* __restrict__ Ciw,
    const short* __restrict__ Dw,
    float* __restrict__ y)
{
  __shared__ short lds[2 * OBUFS];
  f32x4 acc[4][4] = {};
  const int tid = threadIdx.x;
  int mb, nbk;
  map_mn4(blockIdx.x, mb, nbk);
  const int m0 = mb * 128;
  const int o0 = nbk * 256;
  gemm_pl<16>(st_re, Crw, NST, NST, m0, o0, tid, acc, lds);
  gemm_pl<16>(st_im, Ciw, NST, NST, m0, o0, tid, acc, lds);
  gemm_fb(x, Dw, DIN, DIN, DIN, m0, o0, tid, acc, lds);
  const int lane = tid & 63, w = tid >> 6, wm = w >> 2, wn = w & 3;
  const int lr = lane & 15, lq = lane >> 4;
  #pragma unroll
  for (int mi = 0; mi < 4; ++mi)
    #pragma unroll
    for (int j = 0; j < 4; ++j) {
      const size_t m = (size_t)m0 + wm * 64 + mi * 16 + lq * 4 + j;
      #pragma unroll
      for (int ni = 0; ni < 4; ++ni)
        y[m * DOUT + o0 + wn * 64 + ni * 16 + lr] = acc[mi][ni][j];
    }
}

// ---- host launch --------------------------------------------------------------------------
extern "C" void kernel_launch(void* const* d_in, const int* in_sizes, int n_in,
                              void* d_out, int out_size, void* d_ws, size_t ws_size,
                              hipStream_t stream)
{
  (void)in_sizes; (void)n_in; (void)out_size;
  const float* x     = (const float*)d_in[0];
  const float* nulog = (const float*)d_in[1];
  const float* thlog = (const float*)d_in[2];
  const float* glog  = (const float*)d_in[3];
  const float* Bre   = (const float*)d_in[4];
  const float* Bim   = (const float*)d_in[5];
  const float* Cre   = (const float*)d_in[6];
  const float* Cim   = (const float*)d_in[7];
  const float* Dm    = (const float*)d_in[8];
  float* y = (float*)d_out;

  // ws: Bu planes (states overwrite in place) | carry | lam | lamL | gamma | weights | xw
  const size_t PLANE  = (size_t)M_TOT * NST;
  const size_t XPLANE = (size_t)M_TOT * DIN;
  short*  bu_re = (short*)d_ws;
  short*  bu_im = bu_re + PLANE;
  float2* carry = (float2*)(bu_im + PLANE);
  float2* lam   = carry + (size_t)BSZ * NC * NST;
  float2* lamL  = lam + NST;
  float*  gamma = (float*)(lamL + NST);

  char* wp = (char*)(gamma + NST);
  wp = (char*)(((uintptr_t)wp + 255) & ~(uintptr_t)255);
  short* Brw = (short*)wp;                          // single RNE planes
  short* Biw = Brw + (size_t)NST * DIN;
  short* Crw = Biw + (size_t)NST * DIN;
  short* Ciw = Crw + (size_t)DOUT * NST;            // pre-negated
  short* Dw  = Ciw + (size_t)DOUT * NST;
  short* xw  = Dw  + (size_t)DOUT * DIN;            // x single plane (row-major)
  const size_t needed_full = (size_t)((char*)(xw + XPLANE) - (char*)d_ws);
  const bool full = (ws_size >= needed_full);

  const int nB4 = (NST * DIN) / 4, nC4 = (DOUT * NST) / 4, nD4 = (DOUT * DIN) / 4;
  const int nX4 = full ? (int)(XPLANE / 4) : 0;
  const int tot = 2 * nB4 + 2 * nC4 + nD4 + nX4 + NST;   // + params tail
  wround_all<<<(tot + 255) / 256, 256, 0, stream>>>(
      Bre, Bim, Cre, Cim, Dm, x, Brw, Biw, Crw, Ciw, Dw, xw,
      nulog, thlog, glog, lam, lamL, gamma, nB4, nC4, nD4, nX4);

  if (full) {
    bu_mfma<<<512, 512, 0, stream>>>(xw, Brw, Biw, gamma, bu_re, bu_im);
  } else {
    bu_fb<<<1024, 512, 0, stream>>>(x, Brw, Biw, gamma, bu_re, bu_im);
  }

  scan_partial<<<(BSZ * NC * (NST / 2)) / 256, 256, 0, stream>>>(bu_re, bu_im, lam, carry);
  scan_carry<<<(BSZ * NST) / 256, 256, 0, stream>>>(carry, lamL);
  scan_final<<<(BSZ * NC * (NST / 2)) / 256, 256, 0, stream>>>(bu_re, bu_im, lam, carry);

  if (full) {
    out_mfma<<<512, 512, 0, stream>>>(bu_re, bu_im, xw, Crw, Ciw, Dw, y);
  } else {
    out_fb<<<1024, 512, 0, stream>>>(bu_re, bu_im, x, Crw, Ciw, Dw, y);
  }
}

// Round 20
// 296.009 us; speedup vs baseline: 1.0216x; 1.0216x over previous
//
#include <hip/hip_runtime.h>
#include <stdint.h>

// LRU forward: y = Re(scan(lam, gamma*(x@B^T)) @ C^T) + x @ D^T
// Round 20: best-of composition = r18's engine (three separate gemm256 calls in
// out_mfma, 3-buffer LDS, 4 phases, spread stage-issue, vmcnt(4)) + r19's validated
// params-into-wround_all fold. r19's fused out pipeline reverted (it cost +7us via
// per-tile address rematerialization: VALU 17.6->21.4%).

#define BSZ   8
#define TLEN  4096
#define DIN   1024
#define DOUT  1024
#define NST   512
#define M_TOT (BSZ * TLEN)   // 32768
#define NC    32
#define CL    128

// 256-tile engine
#define WOFF  8192           // W region offset (A region = 256x32 shorts = 16KB)
#define NBUF  16384          // shorts per buffer (32KB): A@0, W@8192

// fallback engine (r14, 128x256)
#define PLA   4096
#define OBUFS 12288

typedef __attribute__((ext_vector_type(8))) short bf16x8;
typedef __attribute__((ext_vector_type(4))) float f32x4;

// ---- bf16 helpers -------------------------------------------------------------------------
__device__ __forceinline__ float s2f(short s) {
  unsigned v = ((unsigned)(unsigned short)s) << 16;
  return __builtin_bit_cast(float, v);
}
__device__ __forceinline__ short f2s_rne(float f) {
  unsigned u = __builtin_bit_cast(unsigned, f);
  unsigned r = (u + 0x7FFFu + ((u >> 16) & 1u)) >> 16;
  return (short)r;
}
__device__ __forceinline__ void round8(const float4 v0, const float4 v1, bf16x8& hv) {
  const float f[8] = {v0.x, v0.y, v0.z, v0.w, v1.x, v1.y, v1.z, v1.w};
  #pragma unroll
  for (int j = 0; j < 8; ++j) hv[j] = f2s_rne(f[j]);
}

// ---- async global->LDS, 16B per lane ------------------------------------------------------
__device__ __forceinline__ void gload16(const short* g, short* l) {
  __builtin_amdgcn_global_load_lds(
      (const __attribute__((address_space(1))) void*)g,
      (__attribute__((address_space(3))) void*)l, 16, 0, 0);
}

// Quad-XOR swizzle (r5-r18, measured 0 conflicts): data quad q of row r lives at slot
// quad q^((r>>1)&3); DMA dest linear, SOURCE pre-permuted, ds_read applies the XOR.

// ---- one staging load (chunk ch of a 256-tile: 0-15 A rows, 16-31 W rows) -----------------
__device__ __forceinline__ void stage_one256(
    const short* __restrict__ Ag, const short* __restrict__ Wg,
    const int lda, const int ldb, const int m0, const int n0, const int k0,
    short* lbuf, const int ch, const int lane)
{
  const int q  = (lane & 3) ^ ((lane >> 3) & 3);
  const int gr = lane >> 2;
  const short* g;
  int r0, ld, dst;
  if (ch < 16) { g = Ag; r0 = m0 + ch * 16;        ld = lda; dst = ch * 512; }
  else         { g = Wg; r0 = n0 + (ch - 16) * 16; ld = ldb; dst = WOFF + (ch - 16) * 512; }
  gload16(g + (size_t)(r0 + gr) * ld + k0 + q * 8, lbuf + dst);
}

// ---- 256-tile pipelined GEMM: 8 waves (2m x 4n), wave tile 128x64 -------------------------
// 3-buffer, 4 phases/K-tile, 1 stage load/phase targeting tile k+2, vmcnt(4).
template<int NT>
__device__ __forceinline__ void gemm256(
    const short* __restrict__ Ap, const short* __restrict__ Wp,
    const int lda, const int ldb, const int m0, const int n0, const int tid,
    f32x4 (&acc)[8][4], short* lds)
{
  const int lane = tid & 63, w = tid >> 6, wm = w >> 2, wn = w & 3;
  const int lr = lane & 15, kg = lane >> 4;
  const int qo = (kg ^ ((lr >> 1) & 3)) * 8;

  // prologue: tiles 0,1 -> buf0,buf1 (4 loads each per wave)
  #pragma unroll
  for (int j = 0; j < 4; ++j)
    stage_one256(Ap, Wp, lda, ldb, m0, n0, 0, lds, w * 4 + j, lane);
  #pragma unroll
  for (int j = 0; j < 4; ++j)
    stage_one256(Ap, Wp, lda, ldb, m0, n0, 32, lds + NBUF, w * 4 + j, lane);

  int c0 = 0;                                // buffer index of tile k
  for (int k = 0; k < NT; ++k) {
    short* cur = lds + c0 * NBUF;
    int cs = c0 + 2; if (cs >= 3) cs -= 3;   // buffer for tile k+2
    short* nx2 = lds + cs * NBUF;

    if (k + 1 < NT) asm volatile("s_waitcnt vmcnt(4)" ::: "memory");  // tile-k landed,
    else            asm volatile("s_waitcnt vmcnt(0)" ::: "memory");  // k+1 stays in flight
    __builtin_amdgcn_s_barrier();            // all waves' tile-k DMA visible

    bf16x8 wv[4];
    #pragma unroll
    for (int ph = 0; ph < 4; ++ph) {         // 4 phases, 2 acc-rows each, 8 MFMA
      if (ph == 0) {
        #pragma unroll
        for (int nf = 0; nf < 4; ++nf)
          wv[nf] = *(const bf16x8*)&cur[WOFF + (wn * 64 + nf * 16 + lr) * 32 + qo];
      }
      const int mi0 = ph * 2;
      const bf16x8 a0 = *(const bf16x8*)&cur[(wm * 128 + mi0 * 16 + lr) * 32 + qo];
      const bf16x8 a1 = *(const bf16x8*)&cur[(wm * 128 + (mi0 + 1) * 16 + lr) * 32 + qo];
      if (k + 2 < NT)                        // spread staging: 1 load/phase, tile k+2
        stage_one256(Ap, Wp, lda, ldb, m0, n0, (k + 2) * 32, nx2, w * 4 + ph, lane);
      __builtin_amdgcn_s_barrier();          // phase start: all waves issued reads
      asm volatile("s_waitcnt lgkmcnt(0)" ::: "memory");
      __builtin_amdgcn_sched_barrier(0);     // rule-18 fence
      __builtin_amdgcn_s_setprio(1);
      #pragma unroll
      for (int nf = 0; nf < 4; ++nf) {
        acc[mi0][nf]     = __builtin_amdgcn_mfma_f32_16x16x32_bf16(a0, wv[nf], acc[mi0][nf], 0, 0, 0);
        acc[mi0 + 1][nf] = __builtin_amdgcn_mfma_f32_16x16x32_bf16(a1, wv[nf], acc[mi0 + 1][nf], 0, 0, 0);
      }
      __builtin_amdgcn_s_setprio(0);
      __builtin_amdgcn_s_barrier();          // phase end
    }
    c0 = (c0 == 2) ? 0 : c0 + 1;
  }
}

// ---- XCD map for 512-block grid: 128 m-blocks x 4 n-blocks --------------------------------
__device__ __forceinline__ void map256(const int bid, int& mb, int& nb) {
  const int xcd = bid & 7;
  const int j   = bid >> 3;       // 0..63
  mb = xcd * 16 + (j >> 2);       // 0..127
  nb = j & 3;                     // 0..3
}

// ==================== fallback engine (r14, 128x256 tile) — !full path only ================
__device__ __forceinline__ void stage_cx(
    const short* __restrict__ Ag, const short* __restrict__ Wg,
    const int lda, const int ldb, const int m0, const int n0, const int k0,
    short* lbuf, const int w, const int lane)
{
  const int q  = (lane & 3) ^ ((lane >> 3) & 3);
  const int gr = lane >> 2;
  #pragma unroll
  for (int j = 0; j < 3; ++j) {
    const int ch = w * 3 + j;
    const short* g;
    int r0, ld, dst;
    if (ch < 8) { g = Ag; r0 = m0 + ch * 16;        ld = lda; dst = ch * 512; }
    else        { g = Wg; r0 = n0 + (ch - 8) * 16;  ld = ldb; dst = PLA + (ch - 8) * 512; }
    gload16(g + (size_t)(r0 + gr) * ld + k0 + q * 8, lbuf + dst);
  }
}

__device__ __forceinline__ void gemm_fb(
    const float* __restrict__ Af, const short* __restrict__ Wp,
    const int lda, const int ldb, const int K, const int m0, const int n0, const int tid,
    f32x4 (&acc)[4][4], short* lds)          // single buffer: A@0, W@PLA
{
  const int lane = tid & 63, w = tid >> 6, wm = w >> 2, wn = w & 3;
  const int r = tid & 127, e = (tid >> 7) & 3;
  float4 pa[2];
  {
    const float* p = Af + (size_t)(m0 + r) * lda + e * 8;
    pa[0] = *(const float4*)(p);
    pa[1] = *(const float4*)(p + 4);
  }
  for (int k0 = 0; k0 < K; k0 += 32) {
    __syncthreads();
    {
      bf16x8 hv;
      round8(pa[0], pa[1], hv);
      const int f = (r >> 1) & 3;
      *(bf16x8*)&lds[r * 32 + ((e ^ f) * 8)] = hv;
    }
    {
      const int q = (lane & 3) ^ ((lane >> 3) & 3);
      const int gr = lane >> 2;
      #pragma unroll
      for (int i = 0; i < 2; ++i)
        gload16(Wp + (size_t)(n0 + (2 * w + i) * 16 + gr) * ldb + k0 + q * 8,
                lds + PLA + (2 * w + i) * 512);
    }
    __syncthreads();
    if (k0 + 32 < K) {
      const float* p = Af + (size_t)(m0 + r) * lda + (k0 + 32) + e * 8;
      pa[0] = *(const float4*)(p);
      pa[1] = *(const float4*)(p + 4);
    }
    const int lr = lane & 15, kg = lane >> 4;
    const int qo = (kg ^ ((lr >> 1) & 3)) * 8;
    bf16x8 aw[4], bw[4];
    #pragma unroll
    for (int mi = 0; mi < 4; ++mi)
      aw[mi] = *(const bf16x8*)&lds[(wm * 64 + mi * 16 + lr) * 32 + qo];
    #pragma unroll
    for (int ni = 0; ni < 4; ++ni)
      bw[ni] = *(const bf16x8*)&lds[PLA + (wn * 64 + ni * 16 + lr) * 32 + qo];
    #pragma unroll
    for (int ni = 0; ni < 4; ++ni)
      #pragma unroll
      for (int mi = 0; mi < 4; ++mi)
        acc[mi][ni] = __builtin_amdgcn_mfma_f32_16x16x32_bf16(aw[mi], bw[ni], acc[mi][ni], 0, 0, 0);
  }
  __syncthreads();
}

template<int NT>
__device__ __forceinline__ void gemm_pl(
    const short* __restrict__ Ap, const short* __restrict__ Wp,
    const int lda, const int ldb, const int m0, const int n0, const int tid,
    f32x4 (&acc)[4][4], short* lds)
{
  const int lane = tid & 63, w = tid >> 6, wm = w >> 2, wn = w & 3;
  const int lr = lane & 15, kg = lane >> 4;
  const int qo = (kg ^ ((lr >> 1) & 3)) * 8;
  stage_cx(Ap, Wp, lda, ldb, m0, n0, 0, lds, w, lane);
  for (int k = 0; k < NT; ++k) {
    short* cur = lds + (k & 1) * OBUFS;
    if (k + 1 < NT) {
      stage_cx(Ap, Wp, lda, ldb, m0, n0, (k + 1) * 32, lds + ((k + 1) & 1) * OBUFS, w, lane);
      asm volatile("s_waitcnt vmcnt(3)" ::: "memory");
    } else {
      asm volatile("s_waitcnt vmcnt(0)" ::: "memory");
    }
    __builtin_amdgcn_s_barrier();
    bf16x8 bw[4];
    #pragma unroll
    for (int ph = 0; ph < 2; ++ph) {
      if (ph == 0) {
        #pragma unroll
        for (int ni = 0; ni < 4; ++ni)
          bw[ni] = *(const bf16x8*)&cur[PLA + (wn * 64 + ni * 16 + lr) * 32 + qo];
      }
      const int mi0 = ph * 2;
      const bf16x8 a0 = *(const bf16x8*)&cur[(wm * 64 + mi0 * 16 + lr) * 32 + qo];
      const bf16x8 a1 = *(const bf16x8*)&cur[(wm * 64 + (mi0 + 1) * 16 + lr) * 32 + qo];
      __builtin_amdgcn_s_barrier();
      asm volatile("s_waitcnt lgkmcnt(0)" ::: "memory");
      __builtin_amdgcn_sched_barrier(0);
      __builtin_amdgcn_s_setprio(1);
      #pragma unroll
      for (int ni = 0; ni < 4; ++ni) {
        acc[mi0][ni]     = __builtin_amdgcn_mfma_f32_16x16x32_bf16(a0, bw[ni], acc[mi0][ni], 0, 0, 0);
        acc[mi0 + 1][ni] = __builtin_amdgcn_mfma_f32_16x16x32_bf16(a1, bw[ni], acc[mi0 + 1][ni], 0, 0, 0);
      }
      __builtin_amdgcn_s_setprio(0);
      __builtin_amdgcn_s_barrier();
    }
  }
}

__device__ __forceinline__ void map_mn4(const int bid, int& mb, int& nb) {
  const int xcd = bid & 7;
  const int j   = bid >> 3;
  mb = xcd * 32 + (j >> 2);
  nb = j & 3;
}
// ===========================================================================================

// ---- fused preprocessing: all weight/x planes + scan params in one launch -----------------
__global__ __launch_bounds__(256) void wround_all(
    const float* __restrict__ Bre, const float* __restrict__ Bim,
    const float* __restrict__ Cre, const float* __restrict__ Cim,
    const float* __restrict__ Dm,  const float* __restrict__ x,
    short* __restrict__ Brw, short* __restrict__ Biw,
    short* __restrict__ Crw, short* __restrict__ Ciw,
    short* __restrict__ Dw,  short* __restrict__ xw,
    const float* __restrict__ nulog, const float* __restrict__ thlog,
    const float* __restrict__ glog,
    float2* __restrict__ lam, float2* __restrict__ lamL, float* __restrict__ gamma,
    const int nB4, const int nC4, const int nD4, const int nX4)
{
  int o = blockIdx.x * 256 + threadIdx.x;
  const float* src; short* dst; float sgn = 1.0f;
  if (o < nB4)              { src = Bre; dst = Brw; }
  else if ((o -= nB4) < nB4){ src = Bim; dst = Biw; }
  else if ((o -= nB4) < nC4){ src = Cre; dst = Crw; }
  else if ((o -= nC4) < nC4){ src = Cim; dst = Ciw; sgn = -1.0f; }
  else if ((o -= nC4) < nD4){ src = Dm;  dst = Dw; }
  else if ((o -= nD4) < nX4){ src = x;   dst = xw; }
  else if ((o -= nX4) < NST){               // scan params tail
    const int n = o;
    const float nu = expf(nulog[n]);
    const float th = expf(thlog[n]);
    const float mod = expf(-nu);
    float s, c;
    sincosf(th, &s, &c);
    lam[n] = make_float2(mod * c, mod * s);
    const float modL = expf(-(float)CL * nu);
    float sL, cL;
    sincosf((float)CL * th, &sL, &cL);
    lamL[n] = make_float2(modL * cL, modL * sL);
    gamma[n] = expf(glog[n]);
    return;
  }
  else return;
  const float4 v = ((const float4*)src)[o];
  short4 hv;
  hv.x = f2s_rne(sgn * v.x); hv.y = f2s_rne(sgn * v.y);
  hv.z = f2s_rne(sgn * v.z); hv.w = f2s_rne(sgn * v.w);
  ((short4*)dst)[o] = hv;
}

// ---- kernel 1 (256 engine): Bu = rne(gamma * (x @ [Bre|Bim]^T)) ---------------------------
__global__ __launch_bounds__(512, 2) void bu_mfma(
    const short* __restrict__ xw,
    const short* __restrict__ Brw, const short* __restrict__ Biw,
    const float* __restrict__ gamma,
    short* __restrict__ bu_re, short* __restrict__ bu_im)
{
  __shared__ short lds[3 * NBUF];          // 96 KB
  f32x4 acc[8][4] = {};
  const int tid = threadIdx.x;
  int mb, nbk;
  map256(blockIdx.x, mb, nbk);
  const int m0  = mb * 256;
  const int n0s = nbk * 256;               // 0,256 -> re; 512,768 -> im
  const bool re = (n0s < NST);
  const int nb0 = n0s & (NST - 1);

  gemm256<32>(xw, re ? Brw : Biw, DIN, DIN, m0, nb0, tid, acc, lds);

  short* Hp = re ? bu_re : bu_im;
  const int lane = tid & 63, w = tid >> 6, wm = w >> 2, wn = w & 3;
  const int lr = lane & 15, lq = lane >> 4;
  #pragma unroll
  for (int nf = 0; nf < 4; ++nf) {
    const int nb = nb0 + wn * 64 + nf * 16 + lr;
    const float g = gamma[nb];
    #pragma unroll
    for (int mf = 0; mf < 8; ++mf)
      #pragma unroll
      for (int j = 0; j < 4; ++j) {
        const size_t m = (size_t)m0 + wm * 128 + mf * 16 + lq * 4 + j;
        Hp[m * NST + nb] = f2s_rne(acc[mf][nf][j] * g);
      }
  }
}

// ---- fallback bu (r14 engine) -------------------------------------------------------------
__global__ __launch_bounds__(512, 4) void bu_fb(
    const float* __restrict__ x,
    const short* __restrict__ Brw, const short* __restrict__ Biw,
    const float* __restrict__ gamma,
    short* __restrict__ bu_re, short* __restrict__ bu_im)
{
  __shared__ short lds[2 * OBUFS];
  f32x4 acc[4][4] = {};
  const int tid = threadIdx.x;
  int mb, nbk;
  map_mn4(blockIdx.x, mb, nbk);
  const int m0  = mb * 128;
  const int n0s = nbk * 256;
  const bool re = (n0s < NST);
  const int nb0 = n0s & (NST - 1);
  gemm_fb(x, re ? Brw : Biw, DIN, DIN, DIN, m0, nb0, tid, acc, lds);
  short* Hp = re ? bu_re : bu_im;
  const int lane = tid & 63, w = tid >> 6, wm = w >> 2, wn = w & 3;
  const int lr = lane & 15, lq = lane >> 4;
  #pragma unroll
  for (int ni = 0; ni < 4; ++ni) {
    const int nb = nb0 + wn * 64 + ni * 16 + lr;
    const float g = gamma[nb];
    #pragma unroll
    for (int mi = 0; mi < 4; ++mi)
      #pragma unroll
      for (int j = 0; j < 4; ++j) {
        const size_t m = (size_t)m0 + wm * 64 + mi * 16 + lq * 4 + j;
        Hp[m * NST + nb] = f2s_rne(acc[mi][ni][j] * g);
      }
  }
}

// ---- scan phase 1: 2-n per thread (short2), single-plane Bu -------------------------------
__global__ __launch_bounds__(256) void scan_partial(
    const short* __restrict__ bu_re, const short* __restrict__ bu_im,
    const float2* __restrict__ lam, float2* __restrict__ carry)
{
  const int g = blockIdx.x * 256 + threadIdx.x;
  const int n2 = g & 255;
  const int c  = (g >> 8) & (NC - 1);
  const int b  = g >> 13;
  const int n  = n2 * 2;
  const float2 L0 = lam[n], L1 = lam[n + 1];
  const short2* R = (const short2*)bu_re;
  const short2* I = (const short2*)bu_im;
  size_t idx = ((size_t)b * TLEN + (size_t)c * CL) * (NST / 2) + n2;
  float sr0 = 0.f, si0 = 0.f, sr1 = 0.f, si1 = 0.f;
  #pragma unroll 4
  for (int t = 0; t < CL; ++t, idx += NST / 2) {
    const short2 vr = R[idx], vi = I[idx];
    const float br0 = s2f(vr.x), br1 = s2f(vr.y);
    const float bi0 = s2f(vi.x), bi1 = s2f(vi.y);
    float nr = fmaf(L0.x, sr0, fmaf(-L0.y, si0, br0));
    float ni = fmaf(L0.x, si0, fmaf( L0.y, sr0, bi0));
    sr0 = nr; si0 = ni;
    nr = fmaf(L1.x, sr1, fmaf(-L1.y, si1, br1));
    ni = fmaf(L1.x, si1, fmaf( L1.y, sr1, bi1));
    sr1 = nr; si1 = ni;
  }
  const size_t cb = (size_t)(b * NC + c) * NST + n;
  carry[cb]     = make_float2(sr0, si0);
  carry[cb + 1] = make_float2(sr1, si1);
}

// ---- scan phase 2 -------------------------------------------------------------------------
__global__ __launch_bounds__(256) void scan_carry(
    float2* __restrict__ carry, const float2* __restrict__ lamL)
{
  const int g = blockIdx.x * 256 + threadIdx.x;
  const int n = g & (NST - 1);
  const int b = g >> 9;
  const float2 P = lamL[n];
  float sr = 0.f, si = 0.f;
  for (int c = 0; c < NC; ++c) {
    const size_t idx = (size_t)(b * NC + c) * NST + n;
    const float2 v = carry[idx];
    carry[idx] = make_float2(sr, si);
    const float nr = fmaf(P.x, sr, fmaf(-P.y, si, v.x));
    const float ni = fmaf(P.x, si, fmaf( P.y, sr, v.y));
    sr = nr; si = ni;
  }
}

// ---- scan phase 3: re-scan with carry-in, states overwrite Bu (single bf16) ---------------
__global__ __launch_bounds__(256) void scan_final(
    short* __restrict__ bu_re, short* __restrict__ bu_im,
    const float2* __restrict__ lam, const float2* __restrict__ carry)
{
  const int g = blockIdx.x * 256 + threadIdx.x;
  const int n2 = g & 255;
  const int c  = (g >> 8) & (NC - 1);
  const int b  = g >> 13;
  const int n  = n2 * 2;
  const float2 L0 = lam[n], L1 = lam[n + 1];
  const size_t cb = (size_t)(b * NC + c) * NST + n;
  const float2 ci0 = carry[cb], ci1 = carry[cb + 1];
  short2* R = (short2*)bu_re;
  short2* I = (short2*)bu_im;
  size_t idx = ((size_t)b * TLEN + (size_t)c * CL) * (NST / 2) + n2;
  float sr0 = ci0.x, si0 = ci0.y, sr1 = ci1.x, si1 = ci1.y;
  #pragma unroll 4
  for (int t = 0; t < CL; ++t, idx += NST / 2) {
    const short2 vr = R[idx], vi = I[idx];
    const float br0 = s2f(vr.x), br1 = s2f(vr.y);
    const float bi0 = s2f(vi.x), bi1 = s2f(vi.y);
    float nr = fmaf(L0.x, sr0, fmaf(-L0.y, si0, br0));
    float ni = fmaf(L0.x, si0, fmaf( L0.y, sr0, bi0));
    sr0 = nr; si0 = ni;
    nr = fmaf(L1.x, sr1, fmaf(-L1.y, si1, br1));
    ni = fmaf(L1.x, si1, fmaf( L1.y, sr1, bi1));
    sr1 = nr; si1 = ni;
    short2 so;
    so.x = f2s_rne(sr0); so.y = f2s_rne(sr1);
    R[idx] = so;
    so.x = f2s_rne(si0); so.y = f2s_rne(si1);
    I[idx] = so;
  }
}

// ---- kernel 5 (256 engine): y = st_re@Cre^T - st_im@Cim^T + x@D^T -------------------------
__global__ __launch_bounds__(512, 2) void out_mfma(
    const short* __restrict__ st_re, const short* __restrict__ st_im,
    const short* __restrict__ xw,
    const short* __restrict__ Crw, const short* __restrict__ Ciw,  // Cim pre-negated
    const short* __restrict__ Dw,
    float* __restrict__ y)
{
  __shared__ short lds[3 * NBUF];          // 96 KB
  f32x4 acc[8][4] = {};
  const int tid = threadIdx.x;
  int mb, nbk;
  map256(blockIdx.x, mb, nbk);
  const int m0 = mb * 256;
  const int o0 = nbk * 256;

  gemm256<16>(st_re, Crw, NST, NST, m0, o0, tid, acc, lds);
  gemm256<16>(st_im, Ciw, NST, NST, m0, o0, tid, acc, lds);
  gemm256<32>(xw, Dw, DIN, DIN, m0, o0, tid, acc, lds);

  const int lane = tid & 63, w = tid >> 6, wm = w >> 2, wn = w & 3;
  const int lr = lane & 15, lq = lane >> 4;
  #pragma unroll
  for (int mf = 0; mf < 8; ++mf)
    #pragma unroll
    for (int j = 0; j < 4; ++j) {
      const size_t m = (size_t)m0 + wm * 128 + mf * 16 + lq * 4 + j;
      #pragma unroll
      for (int nf = 0; nf < 4; ++nf)
        y[m * DOUT + o0 + wn * 64 + nf * 16 + lr] = acc[mf][nf][j];
    }
}

// ---- fallback out (r14 engine) ------------------------------------------------------------
__global__ __launch_bounds__(512, 4) void out_fb(
    const short* __restrict__ st_re, const short* __restrict__ st_im,
    const float* __restrict__ x,
    const short* __restrict__ Crw, const short* __restrict__ Ciw,
    const short* __restrict__ Dw,
    float* __restrict__ y)
{
  __shared__ short lds[2 * OBUFS];
  f32x4 acc[4][4] = {};
  const int tid = threadIdx.x;
  int mb, nbk;
  map_mn4(blockIdx.x, mb, nbk);
  const int m0 = mb * 128;
  const int o0 = nbk * 256;
  gemm_pl<16>(st_re, Crw, NST, NST, m0, o0, tid, acc, lds);
  gemm_pl<16>(st_im, Ciw, NST, NST, m0, o0, tid, acc, lds);
  gemm_fb(x, Dw, DIN, DIN, DIN, m0, o0, tid, acc, lds);
  const int lane = tid & 63, w = tid >> 6, wm = w >> 2, wn = w & 3;
  const int lr = lane & 15, lq = lane >> 4;
  #pragma unroll
  for (int mi = 0; mi < 4; ++mi)
    #pragma unroll
    for (int j = 0; j < 4; ++j) {
      const size_t m = (size_t)m0 + wm * 64 + mi * 16 + lq * 4 + j;
      #pragma unroll
      for (int ni = 0; ni < 4; ++ni)
        y[m * DOUT + o0 + wn * 64 + ni * 16 + lr] = acc[mi][ni][j];
    }
}

// ---- host launch --------------------------------------------------------------------------
extern "C" void kernel_launch(void* const* d_in, const int* in_sizes, int n_in,
                              void* d_out, int out_size, void* d_ws, size_t ws_size,
                              hipStream_t stream)
{
  (void)in_sizes; (void)n_in; (void)out_size;
  const float* x     = (const float*)d_in[0];
  const float* nulog = (const float*)d_in[1];
  const float* thlog = (const float*)d_in[2];
  const float* glog  = (const float*)d_in[3];
  const float* Bre   = (const float*)d_in[4];
  const float* Bim   = (const float*)d_in[5];
  const float* Cre   = (const float*)d_in[6];
  const float* Cim   = (const float*)d_in[7];
  const float* Dm    = (const float*)d_in[8];
  float* y = (float*)d_out;

  // ws: Bu planes (states overwrite in place) | carry | lam | lamL | gamma | weights | xw
  const size_t PLANE  = (size_t)M_TOT * NST;
  const size_t XPLANE = (size_t)M_TOT * DIN;
  short*  bu_re = (short*)d_ws;
  short*  bu_im = bu_re + PLANE;
  float2* carry = (float2*)(bu_im + PLANE);
  float2* lam   = carry + (size_t)BSZ * NC * NST;
  float2* lamL  = lam + NST;
  float*  gamma = (float*)(lamL + NST);

  char* wp = (char*)(gamma + NST);
  wp = (char*)(((uintptr_t)wp + 255) & ~(uintptr_t)255);
  short* Brw = (short*)wp;                          // single RNE planes
  short* Biw = Brw + (size_t)NST * DIN;
  short* Crw = Biw + (size_t)NST * DIN;
  short* Ciw = Crw + (size_t)DOUT * NST;            // pre-negated
  short* Dw  = Ciw + (size_t)DOUT * NST;
  short* xw  = Dw  + (size_t)DOUT * DIN;            // x single plane (row-major)
  const size_t needed_full = (size_t)((char*)(xw + XPLANE) - (char*)d_ws);
  const bool full = (ws_size >= needed_full);

  const int nB4 = (NST * DIN) / 4, nC4 = (DOUT * NST) / 4, nD4 = (DOUT * DIN) / 4;
  const int nX4 = full ? (int)(XPLANE / 4) : 0;
  const int tot = 2 * nB4 + 2 * nC4 + nD4 + nX4 + NST;   // + params tail
  wround_all<<<(tot + 255) / 256, 256, 0, stream>>>(
      Bre, Bim, Cre, Cim, Dm, x, Brw, Biw, Crw, Ciw, Dw, xw,
      nulog, thlog, glog, lam, lamL, gamma, nB4, nC4, nD4, nX4);

  if (full) {
    bu_mfma<<<512, 512, 0, stream>>>(xw, Brw, Biw, gamma, bu_re, bu_im);
  } else {
    bu_fb<<<1024, 512, 0, stream>>>(x, Brw, Biw, gamma, bu_re, bu_im);
  }

  scan_partial<<<(BSZ * NC * (NST / 2)) / 256, 256, 0, stream>>>(bu_re, bu_im, lam, carry);
  scan_carry<<<(BSZ * NST) / 256, 256, 0, stream>>>(carry, lamL);
  scan_final<<<(BSZ * NC * (NST / 2)) / 256, 256, 0, stream>>>(bu_re, bu_im, lam, carry);

  if (full) {
    out_mfma<<<512, 512, 0, stream>>>(bu_re, bu_im, xw, Crw, Ciw, Dw, y);
  } else {
    out_fb<<<1024, 512, 0, stream>>>(bu_re, bu_im, x, Crw, Ciw, Dw, y);
  }
}